// Round 2
// baseline (198.793 us; speedup 1.0000x reference)
//
#include <hip/hip_runtime.h>
#include <math.h>

#define INV_SQRT2 0.70710678118654752440
#define PI_D 3.14159265358979323846

// Native clang vector type — __builtin_nontemporal_store requires this
// (HIP's float4 is a class and is rejected).
typedef float vfloat4 __attribute__((ext_vector_type(4)));

// ---------------------------------------------------------------------------
// Compile-time construction of the fixed "J" matrix (rho_l of the rotation
// that conjugates exp(b*Jy) into exp(b*Jx)), replicating the reference's
// generator conventions exactly (verified on-device via runtime expm in a
// previous session; constexpr version matched with absmax 0.0156).
// ---------------------------------------------------------------------------
template <int N> struct MatF { float a[N * N]; };

constexpr double csqrt(double x) {
  if (x <= 0.0) return 0.0;
  double g = x > 1.0 ? x : 1.0;
  for (int i = 0; i < 40; ++i) g = 0.5 * (g + x / g);
  return g;
}

template <int L>
constexpr MatF<2 * L + 1> makeJ() {
  constexpr int n = 2 * L + 1;
  double Qr[n * n] = {}, Qi[n * n] = {};
  for (int r = 0; r < n; ++r) {
    int m = r - L;
    if (m < 0) {
      Qr[r * n + (L - m)] = INV_SQRT2;
      Qi[r * n + (L + m)] = -INV_SQRT2;
    } else if (m == 0) {
      Qr[r * n + L] = 1.0;
    } else {
      double sgn = (m & 1) ? -1.0 : 1.0;
      Qr[r * n + (L + m)] = sgn * INV_SQRT2;
      Qi[r * n + (L - m)] = sgn * INV_SQRT2;
    }
  }
  double c[n] = {};
  for (int i = 0; i + 1 < n; ++i) {
    double m = (double)(i - L);
    c[i] = 0.5 * csqrt((double)(L * (L + 1)) - m * (m + 1.0));
  }
  double Br[n * n] = {}, Bi[n * n] = {};
  for (int i = 0; i < n; ++i)
    for (int j = 0; j < n; ++j) {
      double br = 0, bi = 0;
      if (i + 1 < n) { br += c[i] * Qr[(i + 1) * n + j]; bi += c[i] * Qi[(i + 1) * n + j]; }
      if (i >= 1)    { br -= c[i - 1] * Qr[(i - 1) * n + j]; bi -= c[i - 1] * Qi[(i - 1) * n + j]; }
      Br[i * n + j] = br;
      Bi[i * n + j] = bi;
    }
  double A[n * n] = {};
  for (int i = 0; i < n; ++i)
    for (int j = 0; j < n; ++j) {
      double acc = 0;
      for (int k = 0; k < n; ++k)
        acc += Qr[k * n + i] * Br[k * n + j] + Qi[k * n + i] * Bi[k * n + j];
      if (j == 2 * L - i && i != L) acc += (double)(L - i);  // Jy[i][2l-i] = l-i
      A[i * n + j] = acc * (PI_D * INV_SQRT2) * (1.0 / 64.0);
    }
  double T[n * n] = {}, U[n * n] = {};
  for (int i = 0; i < n; ++i) T[i * n + i] = 1.0;
  for (int k = 10; k >= 1; --k) {
    for (int i = 0; i < n; ++i)
      for (int j = 0; j < n; ++j) {
        double acc = 0;
        for (int q = 0; q < n; ++q) acc += A[i * n + q] * T[q * n + j];
        U[i * n + j] = acc;
      }
    double inv = 1.0 / (double)k;
    for (int i = 0; i < n; ++i)
      for (int j = 0; j < n; ++j)
        T[i * n + j] = ((i == j) ? 1.0 : 0.0) + U[i * n + j] * inv;
  }
  for (int s = 0; s < 6; ++s) {
    for (int i = 0; i < n; ++i)
      for (int j = 0; j < n; ++j) {
        double acc = 0;
        for (int q = 0; q < n; ++q) acc += T[i * n + q] * T[q * n + j];
        U[i * n + j] = acc;
      }
    for (int t = 0; t < n * n; ++t) T[t] = U[t];
  }
  MatF<n> R = {};
  for (int t = 0; t < n * n; ++t) {
    double v = T[t];
    if (v < 1e-9 && v > -1e-9) v = 0.0;  // snap exact zeros -> if-constexpr drops FMA
    R.a[t] = (float)v;
  }
  return R;
}

template <int L> struct JMat { static constexpr MatF<2 * L + 1> M = makeJ<L>(); };

// matJ with GUARANTEED compile-time weights: each J entry is a constexpr float
// (literal operand), zero entries removed by `if constexpr` — no memory loads,
// no runtime tests, regardless of optimizer behavior.
template <int L, int I, int K>
__device__ __forceinline__ float matJ_dot(const float* v) {
  if constexpr (K < 0) {
    return 0.f;
  } else {
    float acc = matJ_dot<L, I, K - 1>(v);
    constexpr float w = JMat<L>::M.a[I * (2 * L + 1) + K];
    if constexpr (w != 0.0f) acc = fmaf(w, v[K], acc);
    return acc;
  }
}

template <int L, int I>
__device__ __forceinline__ void matJ_rows(const float* v, float* o) {
  if constexpr (I >= 0) {
    matJ_rows<L, I - 1>(v, o);
    o[I] = matJ_dot<L, I, 2 * L>(v);
  }
}

template <int L>
__device__ __forceinline__ void matJ(const float* v, float* o) {
  matJ_rows<L, 2 * L>(v, o);
}

// ---------------------------------------------------------------------------
// Shared cos/sin(k*theta) tables, k = 0..6, computed ONCE per angle and reused
// by both L=4 and L=6 (the old code re-ran this recurrence inside each of the
// six rotY calls). Recurrence is bit-identical to the old in-loop one.
// All indices compile-time (full unroll) -> stays in registers.
// ---------------------------------------------------------------------------
struct Trig { float c[7]; float s[7]; };

__device__ __forceinline__ Trig mk_trig(float c1, float s1) {
  Trig t;
  t.c[0] = 1.f; t.s[0] = 0.f;
  t.c[1] = c1;  t.s[1] = s1;
#pragma unroll
  for (int k = 2; k <= 6; ++k) {
    t.c[k] = t.c[k - 1] * c1 - t.s[k - 1] * s1;
    t.s[k] = t.s[k - 1] * c1 + t.c[k - 1] * s1;
  }
  return t;
}

template <int L>
__device__ __forceinline__ void rotY(const Trig& tg, const float* v, float* o) {
  o[L] = v[L];
#pragma unroll
  for (int k = 1; k <= L; k++) {
    o[L - k] =  tg.c[k] * v[L - k] + tg.s[k] * v[L + k];
    o[L + k] = -tg.s[k] * v[L - k] + tg.c[k] * v[L + k];
  }
}

template <int L>
__device__ __forceinline__ void wigner_apply(const float* __restrict__ svec,
                                             const Trig& ta, const Trig& tb,
                                             const Trig& tg, float* f) {
  constexpr int n = 2 * L + 1;
  float t[n], u[n];
  rotY<L>(tg, svec, t);   // exp(gamma*Jy)  (svec uniform -> scalar operands)
  matJ<L>(t, u);          // J
  rotY<L>(tb, u, t);      // exp(beta*Jy)
  matJ<L>(t, u);          // J   => exp(beta*Jx)
  rotY<L>(ta, u, f);      // exp(alpha*Jy)  (f may be an LDS pointer)
}

// ---------------------------------------------------------------------------
// Per-quaternion kernel.
// Pipeline: compute f6 -> barrier -> ISSUE f6 stores (fire-and-forget)
//           -> compute f4 (hides the f6 store drain) -> barrier -> f4 stores.
// __launch_bounds__(256,4): pin >=4 waves/SIMD (VGPR cap 128; est. live ~90).
// ---------------------------------------------------------------------------
__global__ __launch_bounds__(256, 4) void wigner_main(
    const float4* __restrict__ quats,
    const float* __restrict__ s4,
    const float* __restrict__ s6,
    float* __restrict__ out,
    int B) {
  __shared__ __align__(16) float lds6[256 * 13];  // 13312 B
  __shared__ __align__(16) float lds4[256 * 9];   //  9216 B
  const int t = threadIdx.x;
  const int b = blockIdx.x;
  const int i = b * 256 + t;
  const int idx = (i < B) ? i : (B - 1);
  float4 q = quats[idx];

  // quat -> rotation matrix (no trig: c=cos(2*acos(w))=2w^2-1, s=2w*sqrt(1-w^2))
  float w = fminf(fmaxf(q.x, -1.f), 1.f);
  float c = 2.f * w * w - 1.f;
  float s = 2.f * w * sqrtf(fmaxf(1.f - w * w, 0.f));
  float an2 = q.y * q.y + q.z * q.z + q.w * q.w;
  float inv = (an2 > 1e-24f) ? rsqrtf(an2) : 1e12f;
  float ax = q.y * inv, ay = q.z * inv, az = q.w * inv;
  float C = 1.f - c;
  float R00 = c + ax * ax * C, R01 = ax * ay * C - az * s, R02 = ax * az * C + ay * s;
  float R20 = az * ax * C - ay * s, R21 = az * ay * C + ax * s, R22 = c + az * az * C;
  float R11 = c + ay * ay * C;

  // Euler cos/sin straight from matrix entries (no arccos/atan2)
  float vx = R01, vy = R11, vz = R21;
  float n2 = vx * vx + vy * vy + vz * vz;
  float invn = (n2 > 1e-24f) ? rsqrtf(n2) : 1e12f;
  vx = fminf(fmaxf(vx * invn, -1.f), 1.f);
  vy = fminf(fmaxf(vy * invn, -1.f), 1.f);
  vz = fminf(fmaxf(vz * invn, -1.f), 1.f);
  float cb = vy;
  float sb = sqrtf(fmaxf(1.f - cb * cb, 0.f));
  float h2 = vx * vx + vz * vz;
  float ca, sa;
  if (h2 > 1e-30f) { float rh = rsqrtf(h2); ca = vz * rh; sa = vx * rh; }
  else             { ca = 1.f; sa = 0.f; }
  float M00 = ca * R00 - sa * R20;
  float M02 = ca * R02 - sa * R22;
  float g2 = M00 * M00 + M02 * M02;
  float cg, sg;
  if (g2 > 1e-30f) { float rg = rsqrtf(g2); cg = M00 * rg; sg = M02 * rg; }
  else             { cg = 1.f; sg = 0.f; }

  // One shared cos/sin(k*angle) table per angle (k<=6), reused by both L.
  Trig TA = mk_trig(ca, sa);
  Trig TB = mk_trig(cb, sb);
  Trig TG = mk_trig(cg, sg);

  const bool full4 = ((b + 1) * 256 <= B) && ((B & 3) == 0);  // block-uniform

  // ---- f6 (longer compute, bigger store) first ----
  wigner_apply<6>(s6, TA, TB, TG, &lds6[t * 13]);  // stride 13: 2-way, free
  __syncthreads();
  if (full4) {
    // fully-coalesced float4 stores, issued BEFORE f4 compute so the drain
    // overlaps the next ~600 cycles of VALU work (stores need no waitcnt).
    const vfloat4* l6 = (const vfloat4*)lds6;
    vfloat4* o6 = (vfloat4*)(out + (size_t)B * 9 + (size_t)b * 3328);
#pragma unroll
    for (int v = t; v < 832; v += 256)
      __builtin_nontemporal_store(l6[v], &o6[v]);
  } else if (i < B) {
    float* o6 = out + (size_t)B * 9 + (size_t)i * 13;
#pragma unroll
    for (int j = 0; j < 13; j++) o6[j] = lds6[t * 13 + j];
  }

  // ---- f4 while the f6 stores are in flight ----
  wigner_apply<4>(s4, TA, TB, TG, &lds4[t * 9]);   // stride 9: 2-way, free
  __syncthreads();
  if (full4) {
    const vfloat4* l4 = (const vfloat4*)lds4;
    vfloat4* o4 = (vfloat4*)(out + (size_t)b * 2304);
#pragma unroll
    for (int v = t; v < 576; v += 256)
      __builtin_nontemporal_store(l4[v], &o4[v]);
  } else if (i < B) {
    float* o4 = out + (size_t)i * 9;
#pragma unroll
    for (int j = 0; j < 9; j++) o4[j] = lds4[t * 9 + j];
  }
}

extern "C" void kernel_launch(void* const* d_in, const int* in_sizes, int n_in,
                              void* d_out, int out_size, void* d_ws, size_t ws_size,
                              hipStream_t stream) {
  const float4* quats = (const float4*)d_in[0];
  const float* s4 = (const float*)d_in[1];
  const float* s6 = (const float*)d_in[2];
  float* out = (float*)d_out;
  int B = in_sizes[0] / 4;
  int blocks = (B + 255) / 256;
  hipLaunchKernelGGL(wigner_main, dim3(blocks), dim3(256), 0, stream,
                     quats, s4, s6, out, B);
}

// Round 3
// 195.757 us; speedup vs baseline: 1.0155x; 1.0155x over previous
//
#include <hip/hip_runtime.h>
#include <math.h>

#define INV_SQRT2 0.70710678118654752440
#define PI_D 3.14159265358979323846

// ---------------------------------------------------------------------------
// Compile-time construction of the fixed "J" matrix (rho_l of the rotation
// that conjugates exp(b*Jy) into exp(b*Jx)), replicating the reference's
// generator conventions exactly (verified on-device via runtime expm in a
// previous session; constexpr version matched with absmax 0.0156).
// ---------------------------------------------------------------------------
template <int N> struct MatF { float a[N * N]; };

constexpr double csqrt(double x) {
  if (x <= 0.0) return 0.0;
  double g = x > 1.0 ? x : 1.0;
  for (int i = 0; i < 40; ++i) g = 0.5 * (g + x / g);
  return g;
}

template <int L>
constexpr MatF<2 * L + 1> makeJ() {
  constexpr int n = 2 * L + 1;
  double Qr[n * n] = {}, Qi[n * n] = {};
  for (int r = 0; r < n; ++r) {
    int m = r - L;
    if (m < 0) {
      Qr[r * n + (L - m)] = INV_SQRT2;
      Qi[r * n + (L + m)] = -INV_SQRT2;
    } else if (m == 0) {
      Qr[r * n + L] = 1.0;
    } else {
      double sgn = (m & 1) ? -1.0 : 1.0;
      Qr[r * n + (L + m)] = sgn * INV_SQRT2;
      Qi[r * n + (L - m)] = sgn * INV_SQRT2;
    }
  }
  double c[n] = {};
  for (int i = 0; i + 1 < n; ++i) {
    double m = (double)(i - L);
    c[i] = 0.5 * csqrt((double)(L * (L + 1)) - m * (m + 1.0));
  }
  double Br[n * n] = {}, Bi[n * n] = {};
  for (int i = 0; i < n; ++i)
    for (int j = 0; j < n; ++j) {
      double br = 0, bi = 0;
      if (i + 1 < n) { br += c[i] * Qr[(i + 1) * n + j]; bi += c[i] * Qi[(i + 1) * n + j]; }
      if (i >= 1)    { br -= c[i - 1] * Qr[(i - 1) * n + j]; bi -= c[i - 1] * Qi[(i - 1) * n + j]; }
      Br[i * n + j] = br;
      Bi[i * n + j] = bi;
    }
  double A[n * n] = {};
  for (int i = 0; i < n; ++i)
    for (int j = 0; j < n; ++j) {
      double acc = 0;
      for (int k = 0; k < n; ++k)
        acc += Qr[k * n + i] * Br[k * n + j] + Qi[k * n + i] * Bi[k * n + j];
      if (j == 2 * L - i && i != L) acc += (double)(L - i);  // Jy[i][2l-i] = l-i
      A[i * n + j] = acc * (PI_D * INV_SQRT2) * (1.0 / 64.0);
    }
  double T[n * n] = {}, U[n * n] = {};
  for (int i = 0; i < n; ++i) T[i * n + i] = 1.0;
  for (int k = 10; k >= 1; --k) {
    for (int i = 0; i < n; ++i)
      for (int j = 0; j < n; ++j) {
        double acc = 0;
        for (int q = 0; q < n; ++q) acc += A[i * n + q] * T[q * n + j];
        U[i * n + j] = acc;
      }
    double inv = 1.0 / (double)k;
    for (int i = 0; i < n; ++i)
      for (int j = 0; j < n; ++j)
        T[i * n + j] = ((i == j) ? 1.0 : 0.0) + U[i * n + j] * inv;
  }
  for (int s = 0; s < 6; ++s) {
    for (int i = 0; i < n; ++i)
      for (int j = 0; j < n; ++j) {
        double acc = 0;
        for (int q = 0; q < n; ++q) acc += T[i * n + q] * T[q * n + j];
        U[i * n + j] = acc;
      }
    for (int t = 0; t < n * n; ++t) T[t] = U[t];
  }
  MatF<n> R = {};
  for (int t = 0; t < n * n; ++t) {
    double v = T[t];
    if (v < 1e-9 && v > -1e-9) v = 0.0;  // snap exact zeros -> if-constexpr drops FMA
    R.a[t] = (float)v;
  }
  return R;
}

template <int L> struct JMat { static constexpr MatF<2 * L + 1> M = makeJ<L>(); };

// matJ with GUARANTEED compile-time weights: each J entry is a constexpr float
// (literal operand), zero entries removed by `if constexpr` — no memory loads,
// no runtime tests, regardless of optimizer behavior.
template <int L, int I, int K>
__device__ __forceinline__ float matJ_dot(const float* v) {
  if constexpr (K < 0) {
    return 0.f;
  } else {
    float acc = matJ_dot<L, I, K - 1>(v);
    constexpr float w = JMat<L>::M.a[I * (2 * L + 1) + K];
    if constexpr (w != 0.0f) acc = fmaf(w, v[K], acc);
    return acc;
  }
}

template <int L, int I>
__device__ __forceinline__ void matJ_rows(const float* v, float* o) {
  if constexpr (I >= 0) {
    matJ_rows<L, I - 1>(v, o);
    o[I] = matJ_dot<L, I, 2 * L>(v);
  }
}

template <int L>
__device__ __forceinline__ void matJ(const float* v, float* o) {
  matJ_rows<L, 2 * L>(v, o);
}

// ---------------------------------------------------------------------------
// Shared cos/sin(k*theta) tables, k = 0..6, computed ONCE per angle and reused
// by both L=4 and L=6. All indices compile-time (full unroll) -> registers.
// ---------------------------------------------------------------------------
struct Trig { float c[7]; float s[7]; };

__device__ __forceinline__ Trig mk_trig(float c1, float s1) {
  Trig t;
  t.c[0] = 1.f; t.s[0] = 0.f;
  t.c[1] = c1;  t.s[1] = s1;
#pragma unroll
  for (int k = 2; k <= 6; ++k) {
    t.c[k] = t.c[k - 1] * c1 - t.s[k - 1] * s1;
    t.s[k] = t.s[k - 1] * c1 + t.c[k - 1] * s1;
  }
  return t;
}

template <int L>
__device__ __forceinline__ void rotY(const Trig& tg, const float* v, float* o) {
  o[L] = v[L];
#pragma unroll
  for (int k = 1; k <= L; k++) {
    o[L - k] =  tg.c[k] * v[L - k] + tg.s[k] * v[L + k];
    o[L + k] = -tg.s[k] * v[L - k] + tg.c[k] * v[L + k];
  }
}

template <int L>
__device__ __forceinline__ void wigner_apply(const float* __restrict__ svec,
                                             const Trig& ta, const Trig& tb,
                                             const Trig& tg, float* f) {
  constexpr int n = 2 * L + 1;
  float t[n], u[n];
  rotY<L>(tg, svec, t);   // exp(gamma*Jy)  (svec uniform -> scalar operands)
  matJ<L>(t, u);          // J
  rotY<L>(tb, u, t);      // exp(beta*Jy)
  matJ<L>(t, u);          // J   => exp(beta*Jx)
  rotY<L>(ta, u, f);      // exp(alpha*Jy)  (f may be an LDS pointer)
}

// ---------------------------------------------------------------------------
// Per-quaternion kernel.
// Pipeline: compute f6 -> barrier -> ISSUE f6 stores (fire-and-forget)
//           -> compute f4 (hides the f6 store drain) -> barrier -> f4 stores.
// NOTE (R3): no min-waves clause — forcing 4 waves/SIMD caps VGPR at 128 and
// risks scratch spill; let the allocator pick. Plain (cached) stores — the
// fill hits 6.6 TB/s without nt; nt bypasses L2 write-combining.
// ---------------------------------------------------------------------------
__global__ __launch_bounds__(256) void wigner_main(
    const float4* __restrict__ quats,
    const float* __restrict__ s4,
    const float* __restrict__ s6,
    float* __restrict__ out,
    int B) {
  __shared__ __align__(16) float lds6[256 * 13];  // 13312 B
  __shared__ __align__(16) float lds4[256 * 9];   //  9216 B
  const int t = threadIdx.x;
  const int b = blockIdx.x;
  const int i = b * 256 + t;
  const int idx = (i < B) ? i : (B - 1);
  float4 q = quats[idx];

  // quat -> rotation matrix (no trig: c=cos(2*acos(w))=2w^2-1, s=2w*sqrt(1-w^2))
  float w = fminf(fmaxf(q.x, -1.f), 1.f);
  float c = 2.f * w * w - 1.f;
  float s = 2.f * w * sqrtf(fmaxf(1.f - w * w, 0.f));
  float an2 = q.y * q.y + q.z * q.z + q.w * q.w;
  float inv = (an2 > 1e-24f) ? rsqrtf(an2) : 1e12f;
  float ax = q.y * inv, ay = q.z * inv, az = q.w * inv;
  float C = 1.f - c;
  float R00 = c + ax * ax * C, R01 = ax * ay * C - az * s, R02 = ax * az * C + ay * s;
  float R20 = az * ax * C - ay * s, R21 = az * ay * C + ax * s, R22 = c + az * az * C;
  float R11 = c + ay * ay * C;

  // Euler cos/sin straight from matrix entries (no arccos/atan2)
  float vx = R01, vy = R11, vz = R21;
  float n2 = vx * vx + vy * vy + vz * vz;
  float invn = (n2 > 1e-24f) ? rsqrtf(n2) : 1e12f;
  vx = fminf(fmaxf(vx * invn, -1.f), 1.f);
  vy = fminf(fmaxf(vy * invn, -1.f), 1.f);
  vz = fminf(fmaxf(vz * invn, -1.f), 1.f);
  float cb = vy;
  float sb = sqrtf(fmaxf(1.f - cb * cb, 0.f));
  float h2 = vx * vx + vz * vz;
  float ca, sa;
  if (h2 > 1e-30f) { float rh = rsqrtf(h2); ca = vz * rh; sa = vx * rh; }
  else             { ca = 1.f; sa = 0.f; }
  float M00 = ca * R00 - sa * R20;
  float M02 = ca * R02 - sa * R22;
  float g2 = M00 * M00 + M02 * M02;
  float cg, sg;
  if (g2 > 1e-30f) { float rg = rsqrtf(g2); cg = M00 * rg; sg = M02 * rg; }
  else             { cg = 1.f; sg = 0.f; }

  // One shared cos/sin(k*angle) table per angle (k<=6), reused by both L.
  Trig TA = mk_trig(ca, sa);
  Trig TB = mk_trig(cb, sb);
  Trig TG = mk_trig(cg, sg);

  const bool full4 = ((b + 1) * 256 <= B) && ((B & 3) == 0);  // block-uniform

  // ---- f6 (longer compute, bigger store) first ----
  wigner_apply<6>(s6, TA, TB, TG, &lds6[t * 13]);  // stride 13: 2-way, free
  __syncthreads();
  if (full4) {
    // fully-coalesced float4 stores, issued BEFORE f4 compute so the drain
    // overlaps the next ~600 cycles of VALU work (stores need no waitcnt).
    const float4* l6 = (const float4*)lds6;
    float4* o6 = (float4*)(out + (size_t)B * 9 + (size_t)b * 3328);
#pragma unroll
    for (int v = t; v < 832; v += 256) o6[v] = l6[v];
  } else if (i < B) {
    float* o6 = out + (size_t)B * 9 + (size_t)i * 13;
#pragma unroll
    for (int j = 0; j < 13; j++) o6[j] = lds6[t * 13 + j];
  }

  // ---- f4 while the f6 stores are in flight ----
  wigner_apply<4>(s4, TA, TB, TG, &lds4[t * 9]);   // stride 9: 2-way, free
  __syncthreads();
  if (full4) {
    const float4* l4 = (const float4*)lds4;
    float4* o4 = (float4*)(out + (size_t)b * 2304);
#pragma unroll
    for (int v = t; v < 576; v += 256) o4[v] = l4[v];
  } else if (i < B) {
    float* o4 = out + (size_t)i * 9;
#pragma unroll
    for (int j = 0; j < 9; j++) o4[j] = lds4[t * 9 + j];
  }
}

extern "C" void kernel_launch(void* const* d_in, const int* in_sizes, int n_in,
                              void* d_out, int out_size, void* d_ws, size_t ws_size,
                              hipStream_t stream) {
  const float4* quats = (const float4*)d_in[0];
  const float* s4 = (const float*)d_in[1];
  const float* s6 = (const float*)d_in[2];
  float* out = (float*)d_out;
  int B = in_sizes[0] / 4;
  int blocks = (B + 255) / 256;
  hipLaunchKernelGGL(wigner_main, dim3(blocks), dim3(256), 0, stream,
                     quats, s4, s6, out, B);
}